// Round 3
// baseline (27630.725 us; speedup 1.0000x reference)
//
#include <hip/hip_runtime.h>
#include <hip/hip_cooperative_groups.h>

namespace cg = cooperative_groups;

#define T_ 256
#define B_ 64
#define I_ 512
#define H_ 1024
#define O_ 512
#define K_ 8
#define KTOT 1536   // I + H
#define RING 16

// Static device buffers (module-load allocation; no d_ws dependency).
__device__ float g_WT [3072u*1536u];     // [c][k] fp32 transposed [Wx;Wh]
__device__ float g_WoT[512u*1024u];      // [o][h] fp32 transposed Wo
__device__ float g_ring[RING*B_*H_];     // hidden ring, fp32
__device__ int   g_isbf16;               // runtime-probed input dtype

__device__ __forceinline__ float b2f(unsigned short u) {
  return __uint_as_float(((unsigned)u) << 16);
}
__device__ __forceinline__ unsigned short f2b(float f) {
  unsigned u = __float_as_uint(f);
  u += 0x7FFFu + ((u >> 16) & 1u);   // round-to-nearest-even
  return (unsigned short)(u >> 16);
}
// dtype-dispatched scalar load
__device__ __forceinline__ float ldv(const void* p, size_t i, int isb) {
  return isb ? b2f(((const unsigned short*)p)[i]) : ((const float*)p)[i];
}

// ---- probe: decide fp32 vs bf16 by exponent sanity of inputs ~ N(0,1) ----
__global__ void probe_dtype(const unsigned short* __restrict__ xs)
{
  if (threadIdx.x == 0 && blockIdx.x == 0) {
    int crazy = 0;
    for (int i = 0; i < 1024; i++) {
      const unsigned e = (xs[i] >> 7) & 0xFFu;   // bf16 exponent field
      if (e >= 0x86u || (e != 0u && e <= 0x69u)) crazy++;  // |v|>64 or 0<|v|<2^-22
    }
    // true bf16 N(0,1): crazy ~ 0.  fp32-as-ushort: crazy ~ 450.
    g_isbf16 = (crazy < 100) ? 1 : 0;
  }
}

// ---- prep: transpose [Wx;Wh] -> WT[c][k] fp32, Wo -> WoT[o][h] fp32 ----
__global__ __launch_bounds__(256) void prep_transpose(
    const void* __restrict__ Wx,
    const void* __restrict__ Wh,
    const void* __restrict__ Wo)
{
  __shared__ float tile[32][33];
  const int isb = g_isbf16;
  const int tb  = blockIdx.x;
  const int tx  = threadIdx.x & 31;
  const int ty8 = threadIdx.x >> 5;
  if (tb < 48*96) {                       // W_cat is (1536 k) x (3072 c)
    const int tk = tb % 48, tc = tb / 48;
    const int k0 = tk*32, c0 = tc*32;
#pragma unroll
    for (int r = 0; r < 4; r++) {
      const int ty = r*8 + ty8;
      const int k = k0 + ty;
      float v = (k < I_) ? ldv(Wx, (size_t)k*3072 + c0 + tx, isb)
                         : ldv(Wh, (size_t)(k - I_)*3072 + c0 + tx, isb);
      tile[ty][tx] = v;
    }
    __syncthreads();
#pragma unroll
    for (int r = 0; r < 4; r++) {
      const int ty = r*8 + ty8;
      g_WT[(size_t)(c0 + ty)*KTOT + k0 + tx] = tile[tx][ty];
    }
  } else {                                 // Wo is (1024 h) x (512 o)
    const int id = tb - 48*96;             // < 512
    const int th = id & 31, to = id >> 5;
    const int h0 = th*32, o0 = to*32;
#pragma unroll
    for (int r = 0; r < 4; r++) {
      const int ty = r*8 + ty8;
      tile[ty][tx] = ldv(Wo, (size_t)(h0 + ty)*O_ + o0 + tx, isb);
    }
    __syncthreads();
#pragma unroll
    for (int r = 0; r < 4; r++) {
      const int ty = r*8 + ty8;
      g_WoT[(size_t)(o0 + ty)*H_ + h0 + tx] = tile[tx][ty];
    }
  }
}

// ---- prep: hidden_states (8,B,H) -> ring slots 8..15 fp32 ----
__global__ __launch_bounds__(256) void prep_ring(const void* __restrict__ hs)
{
  const int i = blockIdx.x*256 + threadIdx.x;   // 512*256 = 131072 threads
  const int e = i*4;                            // < 524288
  float4 v;
  if (g_isbf16) {
    ushort4 u = *(const ushort4*)((const unsigned short*)hs + e);
    v = make_float4(b2f(u.x), b2f(u.y), b2f(u.z), b2f(u.w));
  } else {
    v = *(const float4*)((const float*)hs + e);
  }
  *(float4*)&g_ring[(size_t)8*B_*H_ + e] = v;
}

// ---- one timestep body, shared by cooperative and per-step kernels ----
__device__ __forceinline__ void do_step(
    int t, int isb,
    const void* __restrict__ x,
    void* __restrict__ out,
    const float* wc, float bz, float br, float bn, float bo_w,
    int tid, int lane, int w, int h0, int o0, int hg,
    float* s, float (*pg)[4][64], float (*po)[4][64])
{
  const bool do_g = (t < T_);   // compute gates/h_t
  const bool do_o = (t > 0);    // compute out[t-1] from h_{t-1}
  const int slot_prev = (t - 1 + RING) & (RING - 1);

  // acc slots: 0-3 z, 4-7 r, 8-11 n_x (x chunks), 12-15 n_h (h chunks)
  float4 acc[16];
#pragma unroll
  for (int i = 0; i < 16; i++) acc[i] = make_float4(0.f, 0.f, 0.f, 0.f);
  float4 ao0 = make_float4(0.f,0.f,0.f,0.f), ao1 = make_float4(0.f,0.f,0.f,0.f);

  for (int cc = (do_g ? 0 : 4); cc < 12; cc++) {
    // ---- stage 64 x 128 chunk into LDS (coalesced, all 256 threads) ----
    if (cc < 4) {
      if (isb) {
#pragma unroll
        for (int it = 0; it < 8; it++) {
          const int f = it*256 + tid;
          const int b = f >> 5;
          const int k = (f & 31) * 4;
          ushort4 u = *(const ushort4*)((const unsigned short*)x
                        + ((size_t)t*B_ + b)*I_ + cc*128 + k);
          *(float4*)&s[b*132 + k] = make_float4(b2f(u.x), b2f(u.y), b2f(u.z), b2f(u.w));
        }
      } else {
#pragma unroll
        for (int it = 0; it < 8; it++) {
          const int f = it*256 + tid;
          const int b = f >> 5;
          const int k = (f & 31) * 4;
          *(float4*)&s[b*132 + k] =
              *(const float4*)((const float*)x + ((size_t)t*B_ + b)*I_ + cc*128 + k);
        }
      }
    } else {
#pragma unroll
      for (int it = 0; it < 8; it++) {
        const int f = it*256 + tid;
        const int b = f >> 5;
        const int k = (f & 31) * 4;
        *(float4*)&s[b*132 + k] =
            *(const float4*)(g_ring + ((size_t)slot_prev*B_ + b)*H_ + (cc-4)*128 + k);
      }
    }
    __syncthreads();

    // my K-quarter of this chunk -> registers
    float4 sv[8];
#pragma unroll
    for (int q = 0; q < 8; q++) sv[q] = *(const float4*)&s[lane*132 + w*32 + q*4];

    if (do_g) {
      const int off = cc*128 + w*32;
      if (cc < 4) {
#pragma unroll
        for (int hl = 0; hl < 4; hl++) {
          const float4* wz = (const float4*)(g_WT + (size_t)(h0 + hl)*KTOT + off);
          const float4* wr = (const float4*)(g_WT + (size_t)(H_ + h0 + hl)*KTOT + off);
          const float4* wn = (const float4*)(g_WT + (size_t)(2*H_ + h0 + hl)*KTOT + off);
          float4 az = acc[hl], ar = acc[4+hl], an = acc[8+hl];
#pragma unroll
          for (int q = 0; q < 8; q++) {
            const float4 sq = sv[q];
            const float4 a  = wz[q];
            az.x += sq.x*a.x;  az.y += sq.y*a.y;  az.z += sq.z*a.z;  az.w += sq.w*a.w;
            const float4 b4 = wr[q];
            ar.x += sq.x*b4.x; ar.y += sq.y*b4.y; ar.z += sq.z*b4.z; ar.w += sq.w*b4.w;
            const float4 c4 = wn[q];
            an.x += sq.x*c4.x; an.y += sq.y*c4.y; an.z += sq.z*c4.z; an.w += sq.w*c4.w;
          }
          acc[hl] = az; acc[4+hl] = ar; acc[8+hl] = an;
        }
      } else {
#pragma unroll
        for (int hl = 0; hl < 4; hl++) {
          const float4* wz = (const float4*)(g_WT + (size_t)(h0 + hl)*KTOT + off);
          const float4* wr = (const float4*)(g_WT + (size_t)(H_ + h0 + hl)*KTOT + off);
          const float4* wn = (const float4*)(g_WT + (size_t)(2*H_ + h0 + hl)*KTOT + off);
          float4 az = acc[hl], ar = acc[4+hl], an = acc[12+hl];
#pragma unroll
          for (int q = 0; q < 8; q++) {
            const float4 sq = sv[q];
            const float4 a  = wz[q];
            az.x += sq.x*a.x;  az.y += sq.y*a.y;  az.z += sq.z*a.z;  az.w += sq.w*a.w;
            const float4 b4 = wr[q];
            ar.x += sq.x*b4.x; ar.y += sq.y*b4.y; ar.z += sq.z*b4.z; ar.w += sq.w*b4.w;
            const float4 c4 = wn[q];
            an.x += sq.x*c4.x; an.y += sq.y*c4.y; an.z += sq.z*c4.z; an.w += sq.w*c4.w;
          }
          acc[hl] = az; acc[4+hl] = ar; acc[12+hl] = an;
        }
      }
    }
    if (do_o && cc >= 4) {
      const int off = (cc - 4)*128 + w*32;
      const float4* w0 = (const float4*)(g_WoT + (size_t)o0*H_ + off);
      const float4* w1 = (const float4*)(g_WoT + (size_t)(o0 + 1)*H_ + off);
#pragma unroll
      for (int q = 0; q < 8; q++) {
        const float4 sq = sv[q];
        const float4 a  = w0[q];
        ao0.x += sq.x*a.x;  ao0.y += sq.y*a.y;  ao0.z += sq.z*a.z;  ao0.w += sq.w*a.w;
        const float4 b4 = w1[q];
        ao1.x += sq.x*b4.x; ao1.y += sq.y*b4.y; ao1.z += sq.z*b4.z; ao1.w += sq.w*b4.w;
      }
    }
    __syncthreads();
  }

  // ---- cross-wave reduction via LDS ----
  if (do_g) {
#pragma unroll
    for (int i = 0; i < 16; i++)
      pg[i][w][lane] = acc[i].x + acc[i].y + acc[i].z + acc[i].w;
  }
  if (do_o) {
    po[0][w][lane] = ao0.x + ao0.y + ao0.z + ao0.w;
    po[1][w][lane] = ao1.x + ao1.y + ao1.z + ao1.w;
  }
  __syncthreads();

  if (do_o && tid < 128) {  // out[t-1][b][o0+w] = h_{t-1} @ Wo + bo
    float v = bo_w + po[w][0][lane] + po[w][1][lane] + po[w][2][lane] + po[w][3][lane];
    const size_t idx = ((size_t)(t - 1)*B_ + lane)*O_ + o0 + w;
    if (isb) ((unsigned short*)out)[idx] = f2b(v);
    else     ((float*)out)[idx] = v;
  }

  if (do_g) {   // gates for h = hg, b = lane
    float pz = bz, pr = br, pnx = bn, pnh = 0.f;
#pragma unroll
    for (int q = 0; q < 4; q++) {
      pz  += pg[w][q][lane];
      pr  += pg[4  + w][q][lane];
      pnx += pg[8  + w][q][lane];
      pnh += pg[12 + w][q][lane];
    }
    const float z = 1.f / (1.f + expf(-pz));
    const float r = 1.f / (1.f + expf(-pr));
    const float n = tanhf(pnx + r*pnh);       // r gates ONLY the h-part
    float mem = 0.f;
#pragma unroll
    for (int j = 0; j < 8; j++) {
      const int sl = (t - 8 + j + RING) & (RING - 1);
      mem += wc[j] * g_ring[((size_t)sl*B_ + lane)*H_ + hg];
    }
    const float hnew = (1.f - z)*n + z*mem;
    g_ring[((size_t)(t & (RING - 1))*B_ + lane)*H_ + hg] = hnew;
  }
}

__device__ __forceinline__ void load_consts(const void* bvec, const void* bov,
                                            const void* mp, int isb,
                                            int hg, int o0, int w,
                                            float* wc, float& bz, float& br,
                                            float& bn, float& bo_w)
{
  const float alpha = 0.5f / (1.0f + expf(-ldv(mp, hg, isb)));
  float c = alpha; float tmp[8]; tmp[0] = c;
#pragma unroll
  for (int i = 1; i < 8; i++) { c *= ((float)i + alpha) / (float)(i + 1); tmp[i] = c; }
#pragma unroll
  for (int j = 0; j < 8; j++) wc[j] = tmp[7 - j];
  bz = ldv(bvec, hg, isb);
  br = ldv(bvec, H_ + hg, isb);
  bn = ldv(bvec, 2*H_ + hg, isb);
  bo_w = (w < 2) ? ldv(bov, o0 + w, isb) : 0.f;
}

__device__ __forceinline__ void write_hfin(int blk, int tid, void* out, int isb)
{
  for (int i = blk*256 + tid; i < (K_*B_*H_)/4; i += 256*256) {
    const int e   = i*4;
    const int j   = e >> 16;          // / (B*H)
    const int rem = e & 65535;
    const int sl  = (T_ - K_ + j) & (RING - 1);
    const float4 v = *(const float4*)&g_ring[(size_t)sl*B_*H_ + rem];
    if (isb) {
      ushort4 o4;
      o4.x = f2b(v.x); o4.y = f2b(v.y); o4.z = f2b(v.z); o4.w = f2b(v.w);
      *(ushort4*)((unsigned short*)out + (size_t)T_*B_*O_ + e) = o4;
    } else {
      *(float4*)((float*)out + (size_t)T_*B_*O_ + e) = v;
    }
  }
}

// ---- persistent cooperative main kernel ----
__global__ __launch_bounds__(256, 1) void mgruf_main(
    const void* __restrict__ x,
    const void* __restrict__ bvec,
    const void* __restrict__ bov,
    const void* __restrict__ mp,
    void* __restrict__ out)
{
  const int isb  = g_isbf16;
  const int tid  = threadIdx.x;
  const int lane = tid & 63;
  const int w    = tid >> 6;
  const int blk  = blockIdx.x;
  const int h0   = blk * 4;
  const int o0   = blk * 2;
  const int hg   = h0 + w;

  __shared__ float s[64*132];
  __shared__ float pg[16][4][64];
  __shared__ float po[2][4][64];

  float wc[8], bz, br, bn, bo_w;
  load_consts(bvec, bov, mp, isb, hg, o0, w, wc, bz, br, bn, bo_w);

  cg::grid_group grid = cg::this_grid();
  for (int t = 0; t <= T_; t++) {
    do_step(t, isb, x, out, wc, bz, br, bn, bo_w, tid, lane, w, h0, o0, hg, s, pg, po);
    grid.sync();
  }
  write_hfin(blk, tid, out, isb);
}

// ---- fallback: one launch per timestep (no grid.sync needed) ----
__global__ __launch_bounds__(256, 1) void mgruf_step(
    int t,
    const void* __restrict__ x,
    const void* __restrict__ bvec,
    const void* __restrict__ bov,
    const void* __restrict__ mp,
    void* __restrict__ out)
{
  const int isb  = g_isbf16;
  const int tid  = threadIdx.x;
  const int lane = tid & 63;
  const int w    = tid >> 6;
  const int blk  = blockIdx.x;
  const int h0   = blk * 4;
  const int o0   = blk * 2;
  const int hg   = h0 + w;

  __shared__ float s[64*132];
  __shared__ float pg[16][4][64];
  __shared__ float po[2][4][64];

  float wc[8], bz, br, bn, bo_w;
  load_consts(bvec, bov, mp, isb, hg, o0, w, wc, bz, br, bn, bo_w);

  do_step(t, isb, x, out, wc, bz, br, bn, bo_w, tid, lane, w, h0, o0, hg, s, pg, po);
  if (t == T_) { __syncthreads(); write_hfin(blk, tid, out, isb); }
}

extern "C" void kernel_launch(void* const* d_in, const int* in_sizes, int n_in,
                              void* d_out, int out_size, void* d_ws, size_t ws_size,
                              hipStream_t stream)
{
  const void* x  = d_in[0];
  const void* hs = d_in[1];
  const void* Wx = d_in[2];
  const void* Wh = d_in[3];
  const void* bv = d_in[4];
  const void* Wo = d_in[5];
  const void* bo = d_in[6];
  const void* mp = d_in[7];
  void* out = d_out;

  probe_dtype<<<dim3(1), dim3(64), 0, stream>>>((const unsigned short*)x);
  prep_transpose<<<dim3(48*96 + 512), dim3(256), 0, stream>>>(Wx, Wh, Wo);
  prep_ring<<<dim3(512), dim3(256), 0, stream>>>(hs);

  void* args[] = { (void*)&x, (void*)&bv, (void*)&bo, (void*)&mp, (void*)&out };
  hipError_t err = hipLaunchCooperativeKernel(
      reinterpret_cast<const void*>(&mgruf_main),
      dim3(256), dim3(256), args, 0u, stream);

  if (err != hipSuccess) {
    // Fallback: sequential per-step launches (identical math, no grid.sync).
    for (int t = 0; t <= T_; t++) {
      mgruf_step<<<dim3(256), dim3(256), 0, stream>>>(t, x, bv, bo, mp, out);
    }
  }
}

// Round 4
// 6066.272 us; speedup vs baseline: 4.5548x; 4.5548x over previous
//
#include <hip/hip_runtime.h>
#include <hip/hip_cooperative_groups.h>

namespace cg = cooperative_groups;

#define T_ 256
#define B_ 64
#define I_ 512
#define H_ 1024
#define O_ 512
#define K_ 8
#define RING 16
#define NGB 64     // gate blocks (each: 16 hidden dims x 3 gates)
#define NOB 32     // out blocks  (each: 16 out cols)
#define NB  (NGB + NOB)
#define SROW 520   // LDS row stride in ushorts (512 + 8 pad -> 2-way banks, free)

typedef unsigned short u16;
typedef __attribute__((ext_vector_type(8))) short short8;
typedef __attribute__((ext_vector_type(4))) float f32x4;

// Static device buffers (module-load allocation; rewritten every call).
__device__ u16   g_xbf [T_*B_*I_];        // x in bf16, 16.8 MB
__device__ u16   g_Bg  [3072u*1536u];     // packed gate B-frags (bf16), 9.44 MB
__device__ u16   g_Bo  [512u*1024u];      // packed out  B-frags (bf16), 1 MB
__device__ u16   g_hbuf[2][B_*H_];        // h in bf16, double-buffered
__device__ float g_ring[RING*B_*H_];      // h history ring, fp32
__device__ int   g_isbf16;

__device__ __forceinline__ float b2f(u16 u) {
  return __uint_as_float(((unsigned)u) << 16);
}
__device__ __forceinline__ u16 f2b(float f) {
  unsigned u = __float_as_uint(f);
  u += 0x7FFFu + ((u >> 16) & 1u);   // RNE
  return (u16)(u >> 16);
}
__device__ __forceinline__ float ldv(const void* p, size_t i, int isb) {
  return isb ? b2f(((const u16*)p)[i]) : ((const float*)p)[i];
}

// ---- probe: fp32 vs bf16 by exponent sanity of inputs ~ N(0,1) ----
__global__ void probe_dtype(const u16* __restrict__ xs)
{
  if (threadIdx.x == 0 && blockIdx.x == 0) {
    int crazy = 0;
    for (int i = 0; i < 1024; i++) {
      const unsigned e = (xs[i] >> 7) & 0xFFu;
      if (e >= 0x86u || (e != 0u && e <= 0x69u)) crazy++;
    }
    g_isbf16 = (crazy < 100) ? 1 : 0;
  }
}

// ---- prep: x -> bf16 ----
__global__ __launch_bounds__(256) void prep_x(const void* __restrict__ x)
{
  const int e = (blockIdx.x*256 + threadIdx.x) * 4;
  ushort4 u;
  if (g_isbf16) {
    u = *(const ushort4*)((const u16*)x + e);
  } else {
    float4 v = *(const float4*)((const float*)x + e);
    u.x = f2b(v.x); u.y = f2b(v.y); u.z = f2b(v.z); u.w = f2b(v.w);
  }
  *(ushort4*)&g_xbf[e] = u;
}

// ---- prep: pack gate weights into B-frag-linear bf16 ----
// dst[((ht*3+g)*48+ks)*512 + lane*8 + j] = Wcat[k = ks*32+(lane>>4)*8+j][c = g*H + ht*16 + (lane&15)]
__global__ __launch_bounds__(256) void prep_pack_g(const void* __restrict__ Wx,
                                                   const void* __restrict__ Wh)
{
  const int isb = g_isbf16;
  const int id  = blockIdx.x*256 + threadIdx.x;      // < 64*3*48*64 = 589824
  const int lane = id & 63;
  const int ks   = (id >> 6) % 48;
  const int g    = ((id >> 6) / 48) % 3;
  const int ht   = (id >> 6) / 144;
  const int c    = g*H_ + ht*16 + (lane & 15);
  const int kb   = ks*32 + (lane >> 4)*8;
  u16 tmp[8];
#pragma unroll
  for (int j = 0; j < 8; j++) {
    const int k = kb + j;
    const float v = (k < I_) ? ldv(Wx, (size_t)k*3072 + c, isb)
                             : ldv(Wh, (size_t)(k - I_)*3072 + c, isb);
    tmp[j] = f2b(v);
  }
  *(ushort4*)&g_Bg[(size_t)id*8]     = make_ushort4(tmp[0],tmp[1],tmp[2],tmp[3]);
  *(ushort4*)&g_Bg[(size_t)id*8 + 4] = make_ushort4(tmp[4],tmp[5],tmp[6],tmp[7]);
}

// ---- prep: pack Wo into B-frag-linear bf16 ----
__global__ __launch_bounds__(256) void prep_pack_o(const void* __restrict__ Wo)
{
  const int isb = g_isbf16;
  const int id  = blockIdx.x*256 + threadIdx.x;      // < 32*32*64 = 65536
  const int lane = id & 63;
  const int ks   = (id >> 6) & 31;
  const int ot   = id >> 11;
  const int c    = ot*16 + (lane & 15);
  const int kb   = ks*32 + (lane >> 4)*8;
  u16 tmp[8];
#pragma unroll
  for (int j = 0; j < 8; j++) {
    const int k = kb + j;
    tmp[j] = f2b(ldv(Wo, (size_t)k*O_ + c, isb));
  }
  *(ushort4*)&g_Bo[(size_t)id*8]     = make_ushort4(tmp[0],tmp[1],tmp[2],tmp[3]);
  *(ushort4*)&g_Bo[(size_t)id*8 + 4] = make_ushort4(tmp[4],tmp[5],tmp[6],tmp[7]);
}

// ---- prep: hidden_states -> ring slots 8..15 (fp32) + hbuf[1] (bf16 h_{-1}) ----
__global__ __launch_bounds__(256) void prep_ring(const void* __restrict__ hs)
{
  const int e = (blockIdx.x*256 + threadIdx.x) * 4;   // < 8*64*1024 = 524288
  float4 v; ushort4 u;
  if (g_isbf16) {
    u = *(const ushort4*)((const u16*)hs + e);
    v = make_float4(b2f(u.x), b2f(u.y), b2f(u.z), b2f(u.w));
  } else {
    v = *(const float4*)((const float*)hs + e);
    u.x = f2b(v.x); u.y = f2b(v.y); u.z = f2b(v.z); u.w = f2b(v.w);
  }
  *(float4*)&g_ring[(size_t)8*B_*H_ + e] = v;
  if (e >= 7*B_*H_) *(ushort4*)&g_hbuf[1][e - 7*B_*H_] = u;  // h_{-1} = hidden_states[7]
}

// ---- one timestep; blk<NGB: gates+h_new; blk>=NGB: out[t-1] ----
__device__ __forceinline__ void step_body(
    int t, int isb, void* __restrict__ out,
    int tid, int lane, int w, int blk,
    const float* wc, float bz, float br, float bn, float bo_c,
    u16* s)
{
  const int quad = lane >> 4, l15 = lane & 15;
  const int m0 = w * 16;

  if (blk < NGB) {
    if (t < T_) {
      f32x4 az = {0.f,0.f,0.f,0.f}, ar = az, anx = az, anh = az;
      const int ht = blk;
      for (int c = 0; c < 3; c++) {
        // stage 64 x 512 bf16 chunk (c=0: x_t; c=1,2: h_{t-1} halves)
#pragma unroll
        for (int it = 0; it < 16; it++) {
          const int idx = it*256 + tid;
          const int row = idx >> 6, col8 = idx & 63;
          const u16* gsrc = (c == 0)
            ? (g_xbf + ((size_t)t*B_ + row)*I_ + col8*8)
            : (g_hbuf[(t-1)&1] + (size_t)row*H_ + (c-1)*512 + col8*8);
          *(short8*)&s[row*SROW + col8*8] = *(const short8*)gsrc;
        }
        __syncthreads();
#pragma unroll 4
        for (int ks = 0; ks < 16; ks++) {
          const short8 a = *(const short8*)&s[(m0 + l15)*SROW + ks*32 + quad*8];
          const int ksg = c*16 + ks;
          const u16* bb = g_Bg + ((size_t)(ht*3)*48 + ksg)*512 + lane*8;
          const short8 b0 = *(const short8*)(bb);
          const short8 b1 = *(const short8*)(bb + 48*512);
          const short8 b2 = *(const short8*)(bb + 2*48*512);
          az = __builtin_amdgcn_mfma_f32_16x16x32_bf16(a, b0, az, 0, 0, 0);
          ar = __builtin_amdgcn_mfma_f32_16x16x32_bf16(a, b1, ar, 0, 0, 0);
          if (c == 0) anx = __builtin_amdgcn_mfma_f32_16x16x32_bf16(a, b2, anx, 0, 0, 0);
          else        anh = __builtin_amdgcn_mfma_f32_16x16x32_bf16(a, b2, anh, 0, 0, 0);
        }
        __syncthreads();
      }
      // epilogue: C layout col=lane&15 (h dim), row=quad*4+reg (batch)  [m89]
      const int hh = ht*16 + l15;
#pragma unroll
      for (int r = 0; r < 4; r++) {
        const int b_r = m0 + quad*4 + r;
        const float z  = 1.f / (1.f + __expf(-(az[r] + bz)));
        const float rr = 1.f / (1.f + __expf(-(ar[r] + br)));
        const float nn = tanhf(anx[r] + bn + rr*anh[r]);
        float mem = 0.f;
#pragma unroll
        for (int j = 0; j < 8; j++) {
          const int sl = (t - 8 + j + 16) & 15;
          mem += wc[j] * g_ring[((size_t)sl*B_ + b_r)*H_ + hh];
        }
        const float hnew = (1.f - z)*nn + z*mem;
        g_ring[((size_t)(t & 15)*B_ + b_r)*H_ + hh] = hnew;
        g_hbuf[t & 1][(size_t)b_r*H_ + hh] = f2b(hnew);
      }
    }
  } else {
    if (t > 0) {
      const int ot = blk - NGB;
      f32x4 ao = {0.f,0.f,0.f,0.f};
      for (int c = 1; c < 3; c++) {
#pragma unroll
        for (int it = 0; it < 16; it++) {
          const int idx = it*256 + tid;
          const int row = idx >> 6, col8 = idx & 63;
          const u16* gsrc = g_hbuf[(t-1)&1] + (size_t)row*H_ + (c-1)*512 + col8*8;
          *(short8*)&s[row*SROW + col8*8] = *(const short8*)gsrc;
        }
        __syncthreads();
#pragma unroll 4
        for (int ks = 0; ks < 16; ks++) {
          const short8 a = *(const short8*)&s[(m0 + l15)*SROW + ks*32 + quad*8];
          const int ksg = (c-1)*16 + ks;
          const short8 b = *(const short8*)(g_Bo + ((size_t)ot*32 + ksg)*512 + lane*8);
          ao = __builtin_amdgcn_mfma_f32_16x16x32_bf16(a, b, ao, 0, 0, 0);
        }
        __syncthreads();
      }
      const int oc = ot*16 + l15;
#pragma unroll
      for (int r = 0; r < 4; r++) {
        const int b_r = m0 + quad*4 + r;
        const float v = ao[r] + bo_c;
        const size_t idx = ((size_t)(t-1)*B_ + b_r)*O_ + oc;
        if (isb) ((u16*)out)[idx] = f2b(v);
        else     ((float*)out)[idx] = v;
      }
    }
  }
}

__device__ __forceinline__ void load_consts(const void* bvec, const void* bov,
                                            const void* mp, int isb, int blk, int lane,
                                            float* wc, float& bz, float& br,
                                            float& bn, float& bo_c)
{
  const int l15 = lane & 15;
  bz = br = bn = bo_c = 0.f;
#pragma unroll
  for (int j = 0; j < 8; j++) wc[j] = 0.f;
  if (blk < NGB) {
    const int hh = blk*16 + l15;
    const float alpha = 0.5f / (1.0f + __expf(-ldv(mp, hh, isb)));
    float cacc = alpha; float tmp[8]; tmp[0] = cacc;
#pragma unroll
    for (int i = 1; i < 8; i++) { cacc *= ((float)i + alpha) / (float)(i + 1); tmp[i] = cacc; }
#pragma unroll
    for (int j = 0; j < 8; j++) wc[j] = tmp[7 - j];
    bz = ldv(bvec, hh, isb);
    br = ldv(bvec, H_ + hh, isb);
    bn = ldv(bvec, 2*H_ + hh, isb);
  } else {
    bo_c = ldv(bov, (blk - NGB)*16 + l15, isb);
  }
}

__device__ __forceinline__ void write_hfin(int blk, int tid, void* out, int isb)
{
  for (int i = blk*256 + tid; i < (K_*B_*H_)/4; i += NB*256) {
    const int e   = i*4;
    const int j   = e >> 16;
    const int rem = e & 65535;
    const int sl  = (T_ - K_ + j) & 15;
    const float4 v = *(const float4*)&g_ring[(size_t)sl*B_*H_ + rem];
    if (isb) {
      ushort4 o4; o4.x = f2b(v.x); o4.y = f2b(v.y); o4.z = f2b(v.z); o4.w = f2b(v.w);
      *(ushort4*)((u16*)out + (size_t)T_*B_*O_ + e) = o4;
    } else {
      *(float4*)((float*)out + (size_t)T_*B_*O_ + e) = v;
    }
  }
}

// ---- persistent cooperative main ----
__global__ __launch_bounds__(256, 1) void mgruf_main(
    const void* __restrict__ bvec, const void* __restrict__ bov,
    const void* __restrict__ mp, void* __restrict__ out)
{
  const int isb = g_isbf16;
  const int tid = threadIdx.x, lane = tid & 63, w = tid >> 6, blk = blockIdx.x;
  __shared__ u16 s[64*SROW];

  float wc[8], bz, br, bn, bo_c;
  load_consts(bvec, bov, mp, isb, blk, lane, wc, bz, br, bn, bo_c);

  cg::grid_group grid = cg::this_grid();
  for (int t = 0; t <= T_; t++) {
    step_body(t, isb, out, tid, lane, w, blk, wc, bz, br, bn, bo_c, s);
    grid.sync();
  }
  write_hfin(blk, tid, out, isb);
}

// ---- fallback: one launch per timestep ----
__global__ __launch_bounds__(256, 1) void mgruf_step(
    int t, const void* __restrict__ bvec, const void* __restrict__ bov,
    const void* __restrict__ mp, void* __restrict__ out)
{
  const int isb = g_isbf16;
  const int tid = threadIdx.x, lane = tid & 63, w = tid >> 6, blk = blockIdx.x;
  __shared__ u16 s[64*SROW];

  float wc[8], bz, br, bn, bo_c;
  load_consts(bvec, bov, mp, isb, blk, lane, wc, bz, br, bn, bo_c);

  step_body(t, isb, out, tid, lane, w, blk, wc, bz, br, bn, bo_c, s);
  if (t == T_) write_hfin(blk, tid, out, isb);
}

extern "C" void kernel_launch(void* const* d_in, const int* in_sizes, int n_in,
                              void* d_out, int out_size, void* d_ws, size_t ws_size,
                              hipStream_t stream)
{
  const void* x  = d_in[0];
  const void* hs = d_in[1];
  const void* Wx = d_in[2];
  const void* Wh = d_in[3];
  const void* bv = d_in[4];
  const void* Wo = d_in[5];
  const void* bo = d_in[6];
  const void* mp = d_in[7];
  void* out = d_out;

  probe_dtype<<<dim3(1), dim3(64), 0, stream>>>((const u16*)x);
  prep_x     <<<dim3(8192), dim3(256), 0, stream>>>(x);
  prep_pack_g<<<dim3(2304), dim3(256), 0, stream>>>(Wx, Wh);
  prep_pack_o<<<dim3(256),  dim3(256), 0, stream>>>(Wo);
  prep_ring  <<<dim3(512),  dim3(256), 0, stream>>>(hs);

  void* args[] = { (void*)&bv, (void*)&bo, (void*)&mp, (void*)&out };
  hipError_t err = hipLaunchCooperativeKernel(
      reinterpret_cast<const void*>(&mgruf_main),
      dim3(NB), dim3(256), args, 0u, stream);

  if (err != hipSuccess) {
    for (int t = 0; t <= T_; t++) {
      mgruf_step<<<dim3(NB), dim3(256), 0, stream>>>(t, bv, bo, mp, out);
    }
  }
}

// Round 6
// 4473.981 us; speedup vs baseline: 6.1759x; 1.3559x over previous
//
#include <hip/hip_runtime.h>

#define T_ 256
#define B_ 64
#define I_ 512
#define H_ 1024
#define O_ 512
#define K_ 8
#define RING 16
#define NLB 32          // loop blocks: each owns 32 hidden dims
#define SROWX 520       // LDS row stride (ushorts) for 512-col tiles
#define SROWH 1032      // LDS row stride (ushorts) for 1024-col tiles

typedef unsigned short u16;
typedef __attribute__((ext_vector_type(8))) short short8;
typedef __attribute__((ext_vector_type(4))) float f32x4;

// Static device buffers (rewritten every call before use).
__device__ u16   g_xbf [T_*B_*I_];          // x bf16, 16.8 MB
__device__ u16   g_Bg  [3072u*1536u];       // gate B-frags bf16 (K-major frag-linear)
__device__ u16   g_Bo  [512u*1024u];        // out  B-frags bf16
__device__ u16   g_hall[(T_+1)*B_*H_];      // h_{-1}..h_{255} bf16, 33.7 MB
__device__ float g_GX  [(size_t)T_*B_*3072];// x@Wx + b, fp32, 201 MB
__device__ float g_ring[RING*B_*H_];        // h history ring fp32
__device__ int   g_isbf16;
__device__ unsigned g_cnt, g_gen;           // barrier state

__device__ __forceinline__ float b2f(u16 u) {
  return __uint_as_float(((unsigned)u) << 16);
}
__device__ __forceinline__ u16 f2b(float f) {
  unsigned u = __float_as_uint(f);
  u += 0x7FFFu + ((u >> 16) & 1u);   // RNE
  return (u16)(u >> 16);
}
__device__ __forceinline__ float ldv(const void* p, size_t i, int isb) {
  return isb ? b2f(((const u16*)p)[i]) : ((const float*)p)[i];
}

// ---- probe dtype + reset barrier state ----
__global__ void probe_dtype(const u16* __restrict__ xs)
{
  if (threadIdx.x == 0 && blockIdx.x == 0) {
    int crazy = 0;
    for (int i = 0; i < 1024; i++) {
      const unsigned e = (xs[i] >> 7) & 0xFFu;
      if (e >= 0x86u || (e != 0u && e <= 0x69u)) crazy++;
    }
    g_isbf16 = (crazy < 100) ? 1 : 0;
    g_cnt = 0u;
    g_gen = 0u;
  }
}

// ---- prep: x -> bf16 ----
__global__ __launch_bounds__(256) void prep_x(const void* __restrict__ x)
{
  const int e = (blockIdx.x*256 + threadIdx.x) * 4;
  ushort4 u;
  if (g_isbf16) {
    u = *(const ushort4*)((const u16*)x + e);
  } else {
    float4 v = *(const float4*)((const float*)x + e);
    u.x = f2b(v.x); u.y = f2b(v.y); u.z = f2b(v.z); u.w = f2b(v.w);
  }
  *(ushort4*)&g_xbf[e] = u;
}

// ---- prep: pack gate weights B-frag-linear ----
// g_Bg[((ht*3+g)*48+ks)*512 + lane*8 + j] = Wcat[ks*32+(lane>>4)*8+j][g*H + ht*16 + (lane&15)]
__global__ __launch_bounds__(256) void prep_pack_g(const void* __restrict__ Wx,
                                                   const void* __restrict__ Wh)
{
  const int isb = g_isbf16;
  const int id  = blockIdx.x*256 + threadIdx.x;      // < 589824
  const int lane = id & 63;
  const int ks   = (id >> 6) % 48;
  const int g    = ((id >> 6) / 48) % 3;
  const int ht   = (id >> 6) / 144;
  const int c    = g*H_ + ht*16 + (lane & 15);
  const int kb   = ks*32 + (lane >> 4)*8;
  u16 tmp[8];
#pragma unroll
  for (int j = 0; j < 8; j++) {
    const int k = kb + j;
    const float v = (k < I_) ? ldv(Wx, (size_t)k*3072 + c, isb)
                             : ldv(Wh, (size_t)(k - I_)*3072 + c, isb);
    tmp[j] = f2b(v);
  }
  *(ushort4*)&g_Bg[(size_t)id*8]     = make_ushort4(tmp[0],tmp[1],tmp[2],tmp[3]);
  *(ushort4*)&g_Bg[(size_t)id*8 + 4] = make_ushort4(tmp[4],tmp[5],tmp[6],tmp[7]);
}

// ---- prep: pack Wo ----
__global__ __launch_bounds__(256) void prep_pack_o(const void* __restrict__ Wo)
{
  const int isb = g_isbf16;
  const int id  = blockIdx.x*256 + threadIdx.x;      // < 65536
  const int lane = id & 63;
  const int ks   = (id >> 6) & 31;
  const int ot   = id >> 11;
  const int c    = ot*16 + (lane & 15);
  const int kb   = ks*32 + (lane >> 4)*8;
  u16 tmp[8];
#pragma unroll
  for (int j = 0; j < 8; j++) tmp[j] = f2b(ldv(Wo, (size_t)(kb + j)*O_ + c, isb));
  *(ushort4*)&g_Bo[(size_t)id*8]     = make_ushort4(tmp[0],tmp[1],tmp[2],tmp[3]);
  *(ushort4*)&g_Bo[(size_t)id*8 + 4] = make_ushort4(tmp[4],tmp[5],tmp[6],tmp[7]);
}

// ---- prep: hidden_states -> ring slots 8..15 fp32; slot 7 -> g_hall[0] bf16 ----
__global__ __launch_bounds__(256) void prep_ring(const void* __restrict__ hs)
{
  const int e = (blockIdx.x*256 + threadIdx.x) * 4;   // < 524288
  float4 v; ushort4 u;
  if (g_isbf16) {
    u = *(const ushort4*)((const u16*)hs + e);
    v = make_float4(b2f(u.x), b2f(u.y), b2f(u.z), b2f(u.w));
  } else {
    v = *(const float4*)((const float*)hs + e);
    u.x = f2b(v.x); u.y = f2b(v.y); u.z = f2b(v.z); u.w = f2b(v.w);
  }
  *(float4*)&g_ring[(size_t)8*B_*H_ + e] = v;
  if (e >= 7*B_*H_) *(ushort4*)&g_hall[e - 7*B_*H_] = u;   // h_{-1}
}

// ---- pre-GEMM: GX[t,b,c] = x_t @ Wx + b  (fp32, bias folded) ----
// grid 1024 = (t, colgroup of 768); 1024 threads.
__global__ __launch_bounds__(1024) void gx_gemm(const void* __restrict__ bvec)
{
  const int isb = g_isbf16;
  const int t  = blockIdx.x >> 2;
  const int cg = blockIdx.x & 3;
  const int tid = threadIdx.x, lane = tid & 63, w = tid >> 6;
  const int m = w & 3, sub = w >> 2;
  const int quad = lane >> 4, l15 = lane & 15;
  __shared__ u16 s[64*SROWX];

#pragma unroll
  for (int it = 0; it < 4; it++) {
    const int idx = it*1024 + tid;
    const int row = idx >> 6, col8 = idx & 63;
    *(short8*)&s[row*SROWX + col8*8] =
        *(const short8*)(g_xbf + ((size_t)t*64 + row)*512 + col8*8);
  }
  __syncthreads();

  const u16* bbase[12];
#pragma unroll
  for (int nt = 0; nt < 12; nt++) {
    const int ct = cg*48 + sub*12 + nt;           // [0,192)
    const int gate = ct >> 6, ht = ct & 63;
    bbase[nt] = g_Bg + ((size_t)(ht*3 + gate)*48)*512 + lane*8;
  }
  f32x4 acc[12];
#pragma unroll
  for (int nt = 0; nt < 12; nt++) acc[nt] = (f32x4){0.f,0.f,0.f,0.f};

  for (int ks = 0; ks < 16; ks++) {
    const short8 a = *(const short8*)&s[(m*16 + l15)*SROWX + ks*32 + quad*8];
#pragma unroll
    for (int nt = 0; nt < 12; nt++) {
      const short8 b = *(const short8*)(bbase[nt] + (size_t)ks*512);
      acc[nt] = __builtin_amdgcn_mfma_f32_16x16x32_bf16(a, b, acc[nt], 0, 0, 0);
    }
  }

#pragma unroll
  for (int nt = 0; nt < 12; nt++) {
    const int ct = cg*48 + sub*12 + nt;
    const int c  = ct*16 + l15;
    const float bias = ldv(bvec, c, isb);
#pragma unroll
    for (int r = 0; r < 4; r++) {
      const int b_row = m*16 + quad*4 + r;
      g_GX[((size_t)t*64 + b_row)*3072 + c] = acc[nt][r] + bias;
    }
  }
}

// ---- the sequential loop: gh = h_{t-1}@Wh, gates, h_t. 32 blocks x 512 thr ----
__global__ __launch_bounds__(512, 1) void mgruf_loop(const void* __restrict__ mp)
{
  const int tid = threadIdx.x, lane = tid & 63, w = tid >> 6, blk = blockIdx.x;
  const int m = w & 3, g = w >> 2;               // m-tile, ht-sub (0..1)
  const int quad = lane >> 4, l15 = lane & 15;
  const int ht = blk*2 + g;
  const int hh = ht*16 + l15;
  __shared__ u16 s[64*SROWH];                    // h_{t-1} staged, 132 KB

  // fractional-memory weights
  float wc[8];
  {
    const float alpha = 0.5f / (1.0f + __expf(-ldv(mp, hh, g_isbf16)));
    float cacc = alpha; float tmp[8]; tmp[0] = cacc;
#pragma unroll
    for (int i = 1; i < 8; i++) { cacc *= ((float)i + alpha)/(float)(i+1); tmp[i] = cacc; }
#pragma unroll
    for (int j = 0; j < 8; j++) wc[j] = tmp[7 - j];
  }
  const u16* pz = g_Bg + ((size_t)(ht*3 + 0)*48 + 16)*512 + lane*8;
  const u16* pr = pz + (size_t)48*512;
  const u16* pn = pz + (size_t)96*512;

  unsigned mygen = 0;

  for (int t = 0; t < T_; t++) {
    // stage h_{t-1} = g_hall[t] (64 x 1024 bf16)
#pragma unroll
    for (int it = 0; it < 16; it++) {
      const int idx = it*512 + tid;
      const int row = idx >> 7, col8 = idx & 127;
      *(short8*)&s[row*SROWH + col8*8] =
          *(const short8*)(g_hall + (size_t)t*B_*H_ + row*1024 + col8*8);
    }
    __syncthreads();

    f32x4 az = {0.f,0.f,0.f,0.f}, ar = az, anh = az;
#pragma unroll 8
    for (int ks = 0; ks < 32; ks++) {
      const short8 a  = *(const short8*)&s[(m*16 + l15)*SROWH + ks*32 + quad*8];
      const short8 bz = *(const short8*)(pz + (size_t)ks*512);
      const short8 br = *(const short8*)(pr + (size_t)ks*512);
      const short8 bn = *(const short8*)(pn + (size_t)ks*512);
      az  = __builtin_amdgcn_mfma_f32_16x16x32_bf16(a, bz, az, 0, 0, 0);
      ar  = __builtin_amdgcn_mfma_f32_16x16x32_bf16(a, br, ar, 0, 0, 0);
      anh = __builtin_amdgcn_mfma_f32_16x16x32_bf16(a, bn, anh, 0, 0, 0);
    }

#pragma unroll
    for (int r = 0; r < 4; r++) {
      const int b = m*16 + quad*4 + r;
      const size_t gxb = ((size_t)t*64 + b)*3072;
      const float gz = g_GX[gxb + hh];
      const float gr = g_GX[gxb + 1024 + hh];
      const float gn = g_GX[gxb + 2048 + hh];
      const float z  = 1.f / (1.f + __expf(-(gz + az[r])));
      const float rr = 1.f / (1.f + __expf(-(gr + ar[r])));
      const float nn = tanhf(gn + rr*anh[r]);
      float mem = 0.f;
#pragma unroll
      for (int j = 0; j < 8; j++) {
        const int sl = (t - 8 + j + 16) & 15;
        mem += wc[j] * g_ring[((size_t)sl*B_ + b)*H_ + hh];
      }
      const float hnew = (1.f - z)*nn + z*mem;
      g_ring[((size_t)(t & 15)*B_ + b)*H_ + hh] = hnew;
      g_hall[(size_t)(t + 1)*B_*H_ + (size_t)b*H_ + hh] = f2b(hnew);
    }

    // ---- custom grid barrier (32 blocks) ----
    __syncthreads();                 // drains each wave's stores per s_barrier semantics
    if (tid == 0) {
      __builtin_amdgcn_fence(__ATOMIC_RELEASE, "agent");
      const unsigned arr = __hip_atomic_fetch_add(&g_cnt, 1u, __ATOMIC_RELAXED,
                                                  __HIP_MEMORY_SCOPE_AGENT);
      if (arr == NLB - 1u) {
        __hip_atomic_store(&g_cnt, 0u, __ATOMIC_RELAXED, __HIP_MEMORY_SCOPE_AGENT);
        __hip_atomic_store(&g_gen, mygen + 1u, __ATOMIC_RELEASE, __HIP_MEMORY_SCOPE_AGENT);
      } else {
        while (__hip_atomic_load(&g_gen, __ATOMIC_RELAXED, __HIP_MEMORY_SCOPE_AGENT) <= mygen)
          __builtin_amdgcn_s_sleep(2);
      }
      __builtin_amdgcn_fence(__ATOMIC_ACQUIRE, "agent");
    }
    mygen++;
    __syncthreads();
  }
}

// ---- fallback loop step (no barrier; one launch per t) ----
__global__ __launch_bounds__(512, 1) void mgruf_loop_step(int t, const void* __restrict__ mp)
{
  const int tid = threadIdx.x, lane = tid & 63, w = tid >> 6, blk = blockIdx.x;
  const int m = w & 3, g = w >> 2;
  const int quad = lane >> 4, l15 = lane & 15;
  const int ht = blk*2 + g;
  const int hh = ht*16 + l15;
  __shared__ u16 s[64*SROWH];

  float wc[8];
  {
    const float alpha = 0.5f / (1.0f + __expf(-ldv(mp, hh, g_isbf16)));
    float cacc = alpha; float tmp[8]; tmp[0] = cacc;
#pragma unroll
    for (int i = 1; i < 8; i++) { cacc *= ((float)i + alpha)/(float)(i+1); tmp[i] = cacc; }
#pragma unroll
    for (int j = 0; j < 8; j++) wc[j] = tmp[7 - j];
  }
  const u16* pz = g_Bg + ((size_t)(ht*3 + 0)*48 + 16)*512 + lane*8;
  const u16* pr = pz + (size_t)48*512;
  const u16* pn = pz + (size_t)96*512;

#pragma unroll
  for (int it = 0; it < 16; it++) {
    const int idx = it*512 + tid;
    const int row = idx >> 7, col8 = idx & 127;
    *(short8*)&s[row*SROWH + col8*8] =
        *(const short8*)(g_hall + (size_t)t*B_*H_ + row*1024 + col8*8);
  }
  __syncthreads();

  f32x4 az = {0.f,0.f,0.f,0.f}, ar = az, anh = az;
#pragma unroll 8
  for (int ks = 0; ks < 32; ks++) {
    const short8 a  = *(const short8*)&s[(m*16 + l15)*SROWH + ks*32 + quad*8];
    const short8 bz = *(const short8*)(pz + (size_t)ks*512);
    const short8 br = *(const short8*)(pr + (size_t)ks*512);
    const short8 bn = *(const short8*)(pn + (size_t)ks*512);
    az  = __builtin_amdgcn_mfma_f32_16x16x32_bf16(a, bz, az, 0, 0, 0);
    ar  = __builtin_amdgcn_mfma_f32_16x16x32_bf16(a, br, ar, 0, 0, 0);
    anh = __builtin_amdgcn_mfma_f32_16x16x32_bf16(a, bn, anh, 0, 0, 0);
  }

#pragma unroll
  for (int r = 0; r < 4; r++) {
    const int b = m*16 + quad*4 + r;
    const size_t gxb = ((size_t)t*64 + b)*3072;
    const float gz = g_GX[gxb + hh];
    const float gr = g_GX[gxb + 1024 + hh];
    const float gn = g_GX[gxb + 2048 + hh];
    const float z  = 1.f / (1.f + __expf(-(gz + az[r])));
    const float rr = 1.f / (1.f + __expf(-(gr + ar[r])));
    const float nn = tanhf(gn + rr*anh[r]);
    float mem = 0.f;
#pragma unroll
    for (int j = 0; j < 8; j++) {
      const int sl = (t - 8 + j + 16) & 15;
      mem += wc[j] * g_ring[((size_t)sl*B_ + b)*H_ + hh];
    }
    const float hnew = (1.f - z)*nn + z*mem;
    g_ring[((size_t)(t & 15)*B_ + b)*H_ + hh] = hnew;
    g_hall[(size_t)(t + 1)*B_*H_ + (size_t)b*H_ + hh] = f2b(hnew);
  }
}

// ---- post-GEMM: out[t] = h_t @ Wo + bo.  grid 256 (one t each), 1024 thr ----
__global__ __launch_bounds__(1024) void out_gemm(const void* __restrict__ bov,
                                                 void* __restrict__ out)
{
  const int isb = g_isbf16;
  const int t = blockIdx.x;
  const int tid = threadIdx.x, lane = tid & 63, w = tid >> 6;
  const int m = w & 3, sub = w >> 2;
  const int quad = lane >> 4, l15 = lane & 15;
  __shared__ u16 s[64*SROWH];

#pragma unroll
  for (int it = 0; it < 8; it++) {
    const int idx = it*1024 + tid;
    const int row = idx >> 7, col8 = idx & 127;
    *(short8*)&s[row*SROWH + col8*8] =
        *(const short8*)(g_hall + (size_t)(t + 1)*B_*H_ + row*1024 + col8*8);
  }
  __syncthreads();

  f32x4 acc[8];
#pragma unroll
  for (int nt = 0; nt < 8; nt++) acc[nt] = (f32x4){0.f,0.f,0.f,0.f};

  for (int ks = 0; ks < 32; ks++) {
    const short8 a = *(const short8*)&s[(m*16 + l15)*SROWH + ks*32 + quad*8];
#pragma unroll
    for (int nt = 0; nt < 8; nt++) {
      const short8 b = *(const short8*)(g_Bo + ((size_t)(sub*8 + nt)*32 + ks)*512 + lane*8);
      acc[nt] = __builtin_amdgcn_mfma_f32_16x16x32_bf16(a, b, acc[nt], 0, 0, 0);
    }
  }

#pragma unroll
  for (int nt = 0; nt < 8; nt++) {
    const int oc = (sub*8 + nt)*16 + l15;
    const float bias = ldv(bov, oc, isb);
#pragma unroll
    for (int r = 0; r < 4; r++) {
      const int b = m*16 + quad*4 + r;
      const float v = acc[nt][r] + bias;
      const size_t idx = ((size_t)t*B_ + b)*O_ + oc;
      if (isb) ((u16*)out)[idx] = f2b(v);
      else     ((float*)out)[idx] = v;
    }
  }
}

// ---- H_fin from ring: 512 blocks x 256 thr x 4 elems = 524288 (exact cover) ----
__global__ __launch_bounds__(256) void hfin_kernel(void* __restrict__ out)
{
  const int isb = g_isbf16;
  const int i = blockIdx.x*256 + threadIdx.x;   // < 131072
  const int e   = i*4;                          // < 524288
  const int j   = e >> 16;                      // / (B*H)
  const int rem = e & 65535;
  const int sl  = (T_ - K_ + j) & 15;
  const float4 v = *(const float4*)&g_ring[(size_t)sl*B_*H_ + rem];
  if (isb) {
    ushort4 o4; o4.x = f2b(v.x); o4.y = f2b(v.y); o4.z = f2b(v.z); o4.w = f2b(v.w);
    *(ushort4*)((u16*)out + (size_t)T_*B_*O_ + e) = o4;
  } else {
    *(float4*)((float*)out + (size_t)T_*B_*O_ + e) = v;
  }
}

extern "C" void kernel_launch(void* const* d_in, const int* in_sizes, int n_in,
                              void* d_out, int out_size, void* d_ws, size_t ws_size,
                              hipStream_t stream)
{
  const void* x  = d_in[0];
  const void* hs = d_in[1];
  const void* Wx = d_in[2];
  const void* Wh = d_in[3];
  const void* bv = d_in[4];
  const void* Wo = d_in[5];
  const void* bo = d_in[6];
  const void* mp = d_in[7];
  void* out = d_out;

  probe_dtype<<<dim3(1), dim3(64), 0, stream>>>((const u16*)x);
  prep_x     <<<dim3(8192), dim3(256), 0, stream>>>(x);
  prep_pack_g<<<dim3(2304), dim3(256), 0, stream>>>(Wx, Wh);
  prep_pack_o<<<dim3(256),  dim3(256), 0, stream>>>(Wo);
  prep_ring  <<<dim3(512),  dim3(256), 0, stream>>>(hs);
  gx_gemm    <<<dim3(1024), dim3(1024), 0, stream>>>(bv);

  void* args[] = { (void*)&mp };
  hipError_t err = hipLaunchCooperativeKernel(
      reinterpret_cast<const void*>(&mgruf_loop),
      dim3(NLB), dim3(512), args, 0u, stream);
  if (err != hipSuccess) {
    for (int t = 0; t < T_; t++)
      mgruf_loop_step<<<dim3(NLB), dim3(512), 0, stream>>>(t, mp);
  }

  out_gemm   <<<dim3(256), dim3(1024), 0, stream>>>(bo, out);
  hfin_kernel<<<dim3(512), dim3(256), 0, stream>>>(out);
}

// Round 7
// 4139.710 us; speedup vs baseline: 6.6746x; 1.0807x over previous
//
#include <hip/hip_runtime.h>

#define T_ 256
#define B_ 64
#define I_ 512
#define H_ 1024
#define O_ 512
#define K_ 8
#define RING 16
#define NLB 32          // loop blocks: each owns 32 hidden dims
#define SROWX 520       // LDS row stride (ushorts) for 512-col tiles
#define SROWH 1032      // LDS row stride (ushorts) for 1024-col tiles

typedef unsigned short u16;
typedef __attribute__((ext_vector_type(8))) short short8;
typedef __attribute__((ext_vector_type(4))) float f32x4;
typedef __attribute__((ext_vector_type(4))) int   i32x4;

// Static device buffers (rewritten every call before use).
__device__ u16   g_xbf [T_*B_*I_];          // x bf16, 16.8 MB
__device__ u16   g_Bg  [3072u*1536u];       // gate B-frags bf16 (K-major frag-linear)
__device__ u16   g_Bo  [512u*1024u];        // out  B-frags bf16
__device__ u16   g_hall[(T_+1)*B_*H_];      // h_{-1}..h_{255} bf16, 33.7 MB
__device__ float g_GX  [(size_t)T_*B_*3072];// x@Wx + b, fp32, 201 MB
__device__ float g_ring[RING*B_*H_];        // h history ring fp32 (block-private cols)
__device__ int   g_isbf16;
__device__ unsigned g_cnt, g_gen;           // barrier state (monotonic)

__device__ __forceinline__ float b2f(u16 u) {
  return __uint_as_float(((unsigned)u) << 16);
}
__device__ __forceinline__ u16 f2b(float f) {
  unsigned u = __float_as_uint(f);
  u += 0x7FFFu + ((u >> 16) & 1u);   // RNE
  return (u16)(u >> 16);
}
__device__ __forceinline__ float ldv(const void* p, size_t i, int isb) {
  return isb ? b2f(((const u16*)p)[i]) : ((const float*)p)[i];
}

// device-coherent (L2-bypassing, write-through) 16B ops
__device__ __forceinline__ void coh_load16(i32x4& dst, const void* p) {
  asm volatile("global_load_dwordx4 %0, %1, off sc0 sc1"
               : "=v"(dst) : "v"(p) : "memory");
}
__device__ __forceinline__ void coh_store16(void* p, i32x4 d) {
  asm volatile("global_store_dwordx4 %0, %1, off sc0 sc1"
               :: "v"(p), "v"(d) : "memory");
}
__device__ __forceinline__ void wait_vm0() {
  asm volatile("s_waitcnt vmcnt(0)" ::: "memory");
}

// ---- probe dtype + reset barrier state ----
__global__ void probe_dtype(const u16* __restrict__ xs)
{
  if (threadIdx.x == 0 && blockIdx.x == 0) {
    int crazy = 0;
    for (int i = 0; i < 1024; i++) {
      const unsigned e = (xs[i] >> 7) & 0xFFu;
      if (e >= 0x86u || (e != 0u && e <= 0x69u)) crazy++;
    }
    g_isbf16 = (crazy < 100) ? 1 : 0;
    g_cnt = 0u;
    g_gen = 0u;
  }
}

// ---- prep: x -> bf16 ----
__global__ __launch_bounds__(256) void prep_x(const void* __restrict__ x)
{
  const int e = (blockIdx.x*256 + threadIdx.x) * 4;
  ushort4 u;
  if (g_isbf16) {
    u = *(const ushort4*)((const u16*)x + e);
  } else {
    float4 v = *(const float4*)((const float*)x + e);
    u.x = f2b(v.x); u.y = f2b(v.y); u.z = f2b(v.z); u.w = f2b(v.w);
  }
  *(ushort4*)&g_xbf[e] = u;
}

// ---- prep: pack gate weights B-frag-linear ----
// g_Bg[((ht*3+g)*48+ks)*512 + lane*8 + j] = Wcat[ks*32+(lane>>4)*8+j][g*H + ht*16 + (lane&15)]
__global__ __launch_bounds__(256) void prep_pack_g(const void* __restrict__ Wx,
                                                   const void* __restrict__ Wh)
{
  const int isb = g_isbf16;
  const int id  = blockIdx.x*256 + threadIdx.x;      // < 589824
  const int lane = id & 63;
  const int ks   = (id >> 6) % 48;
  const int g    = ((id >> 6) / 48) % 3;
  const int ht   = (id >> 6) / 144;
  const int c    = g*H_ + ht*16 + (lane & 15);
  const int kb   = ks*32 + (lane >> 4)*8;
  u16 tmp[8];
#pragma unroll
  for (int j = 0; j < 8; j++) {
    const int k = kb + j;
    const float v = (k < I_) ? ldv(Wx, (size_t)k*3072 + c, isb)
                             : ldv(Wh, (size_t)(k - I_)*3072 + c, isb);
    tmp[j] = f2b(v);
  }
  *(ushort4*)&g_Bg[(size_t)id*8]     = make_ushort4(tmp[0],tmp[1],tmp[2],tmp[3]);
  *(ushort4*)&g_Bg[(size_t)id*8 + 4] = make_ushort4(tmp[4],tmp[5],tmp[6],tmp[7]);
}

// ---- prep: pack Wo ----
__global__ __launch_bounds__(256) void prep_pack_o(const void* __restrict__ Wo)
{
  const int isb = g_isbf16;
  const int id  = blockIdx.x*256 + threadIdx.x;      // < 65536
  const int lane = id & 63;
  const int ks   = (id >> 6) & 31;
  const int ot   = id >> 11;
  const int c    = ot*16 + (lane & 15);
  const int kb   = ks*32 + (lane >> 4)*8;
  u16 tmp[8];
#pragma unroll
  for (int j = 0; j < 8; j++) tmp[j] = f2b(ldv(Wo, (size_t)(kb + j)*O_ + c, isb));
  *(ushort4*)&g_Bo[(size_t)id*8]     = make_ushort4(tmp[0],tmp[1],tmp[2],tmp[3]);
  *(ushort4*)&g_Bo[(size_t)id*8 + 4] = make_ushort4(tmp[4],tmp[5],tmp[6],tmp[7]);
}

// ---- prep: hidden_states -> ring slots 8..15 fp32; slot 7 -> g_hall[0] bf16 ----
__global__ __launch_bounds__(256) void prep_ring(const void* __restrict__ hs)
{
  const int e = (blockIdx.x*256 + threadIdx.x) * 4;   // < 524288
  float4 v; ushort4 u;
  if (g_isbf16) {
    u = *(const ushort4*)((const u16*)hs + e);
    v = make_float4(b2f(u.x), b2f(u.y), b2f(u.z), b2f(u.w));
  } else {
    v = *(const float4*)((const float*)hs + e);
    u.x = f2b(v.x); u.y = f2b(v.y); u.z = f2b(v.z); u.w = f2b(v.w);
  }
  *(float4*)&g_ring[(size_t)8*B_*H_ + e] = v;
  if (e >= 7*B_*H_) *(ushort4*)&g_hall[e - 7*B_*H_] = u;   // h_{-1}
}

// ---- pre-GEMM: GX[t,b,c] = x_t @ Wx + b  (fp32, bias folded) ----
__global__ __launch_bounds__(1024) void gx_gemm(const void* __restrict__ bvec)
{
  const int isb = g_isbf16;
  const int t  = blockIdx.x >> 2;
  const int cg = blockIdx.x & 3;
  const int tid = threadIdx.x, lane = tid & 63, w = tid >> 6;
  const int m = w & 3, sub = w >> 2;
  const int quad = lane >> 4, l15 = lane & 15;
  __shared__ u16 s[64*SROWX];

#pragma unroll
  for (int it = 0; it < 4; it++) {
    const int idx = it*1024 + tid;
    const int row = idx >> 6, col8 = idx & 63;
    *(short8*)&s[row*SROWX + col8*8] =
        *(const short8*)(g_xbf + ((size_t)t*64 + row)*512 + col8*8);
  }
  __syncthreads();

  const u16* bbase[12];
#pragma unroll
  for (int nt = 0; nt < 12; nt++) {
    const int ct = cg*48 + sub*12 + nt;           // [0,192)
    const int gate = ct >> 6, ht = ct & 63;
    bbase[nt] = g_Bg + ((size_t)(ht*3 + gate)*48)*512 + lane*8;
  }
  f32x4 acc[12];
#pragma unroll
  for (int nt = 0; nt < 12; nt++) acc[nt] = (f32x4){0.f,0.f,0.f,0.f};

  for (int ks = 0; ks < 16; ks++) {
    const short8 a = *(const short8*)&s[(m*16 + l15)*SROWX + ks*32 + quad*8];
#pragma unroll
    for (int nt = 0; nt < 12; nt++) {
      const short8 b = *(const short8*)(bbase[nt] + (size_t)ks*512);
      acc[nt] = __builtin_amdgcn_mfma_f32_16x16x32_bf16(a, b, acc[nt], 0, 0, 0);
    }
  }

#pragma unroll
  for (int nt = 0; nt < 12; nt++) {
    const int ct = cg*48 + sub*12 + nt;
    const int c  = ct*16 + l15;
    const float bias = ldv(bvec, c, isb);
#pragma unroll
    for (int r = 0; r < 4; r++) {
      const int b_row = m*16 + quad*4 + r;
      g_GX[((size_t)t*64 + b_row)*3072 + c] = acc[nt][r] + bias;
    }
  }
}

// ---- the sequential loop: gh = h_{t-1}@Wh, gates, h_t. 32 blocks x 512 thr ----
__global__ __launch_bounds__(512, 1) void mgruf_loop(const void* __restrict__ mp)
{
  const int tid = threadIdx.x, lane = tid & 63, w = tid >> 6, blk = blockIdx.x;
  const int m = w & 3, g = w >> 2;               // m-tile, ht-sub (0..1)
  const int quad = lane >> 4, l15 = lane & 15;
  const int ht = blk*2 + g;
  const int hh = ht*16 + l15;
  __shared__ u16 s [64*SROWH];                   // h_{t-1} staged, 129 KB
  __shared__ u16 s2[64*32];                      // h_new transpose buf, 4 KB

  float wc[8];
  {
    const float alpha = 0.5f / (1.0f + __expf(-ldv(mp, hh, g_isbf16)));
    float cacc = alpha; float tmp[8]; tmp[0] = cacc;
#pragma unroll
    for (int i = 1; i < 8; i++) { cacc *= ((float)i + alpha)/(float)(i+1); tmp[i] = cacc; }
#pragma unroll
    for (int j = 0; j < 8; j++) wc[j] = tmp[7 - j];
  }
  const u16* pz = g_Bg + ((size_t)(ht*3 + 0)*48 + 16)*512 + lane*8;
  const u16* pr = pz + (size_t)48*512;
  const u16* pn = pz + (size_t)96*512;

  unsigned mygen = 0;

  for (int t = 0; t < T_; t++) {
    // ---- coherent staging of h_{t-1} (sourced at/through L3; no L2 staleness) ----
    {
      i32x4 tmp[16];
      const u16* hsrc = g_hall + (size_t)t*B_*H_;
#pragma unroll
      for (int it = 0; it < 16; it++) {
        coh_load16(tmp[it], hsrc + (size_t)(it*512 + tid)*8);
      }
      wait_vm0();
#pragma unroll
      for (int it = 0; it < 16; it++) {
        const int idx = it*512 + tid;
        const int row = idx >> 7, col8 = idx & 127;
        *(i32x4*)&s[row*SROWH + col8*8] = tmp[it];
      }
    }
    __syncthreads();

    // hoisted epilogue operands (independent of staged h) — overlap with MFMA
    float gxv[3][4], rv[8][4];
#pragma unroll
    for (int r = 0; r < 4; r++) {
      const int b = m*16 + quad*4 + r;
      const size_t gxb = ((size_t)t*64 + b)*3072;
      gxv[0][r] = g_GX[gxb + hh];
      gxv[1][r] = g_GX[gxb + 1024 + hh];
      gxv[2][r] = g_GX[gxb + 2048 + hh];
#pragma unroll
      for (int j = 0; j < 8; j++) {
        const int sl = (t - 8 + j + 16) & 15;
        rv[j][r] = g_ring[((size_t)sl*B_ + b)*H_ + hh];
      }
    }

    f32x4 az = {0.f,0.f,0.f,0.f}, ar = az, anh = az;
#pragma unroll 8
    for (int ks = 0; ks < 32; ks++) {
      const short8 a  = *(const short8*)&s[(m*16 + l15)*SROWH + ks*32 + quad*8];
      const short8 bz = *(const short8*)(pz + (size_t)ks*512);
      const short8 br = *(const short8*)(pr + (size_t)ks*512);
      const short8 bn = *(const short8*)(pn + (size_t)ks*512);
      az  = __builtin_amdgcn_mfma_f32_16x16x32_bf16(a, bz, az, 0, 0, 0);
      ar  = __builtin_amdgcn_mfma_f32_16x16x32_bf16(a, br, ar, 0, 0, 0);
      anh = __builtin_amdgcn_mfma_f32_16x16x32_bf16(a, bn, anh, 0, 0, 0);
    }

#pragma unroll
    for (int r = 0; r < 4; r++) {
      const int b = m*16 + quad*4 + r;
      const float z  = 1.f / (1.f + __expf(-(gxv[0][r] + az[r])));
      const float rr = 1.f / (1.f + __expf(-(gxv[1][r] + ar[r])));
      const float nn = tanhf(gxv[2][r] + rr*anh[r]);
      float mem = 0.f;
#pragma unroll
      for (int j = 0; j < 8; j++) mem += wc[j] * rv[j][r];
      const float hnew = (1.f - z)*nn + z*mem;
      g_ring[((size_t)(t & 15)*B_ + b)*H_ + hh] = hnew;   // block-private cols, cached
      s2[b*32 + g*16 + l15] = f2b(hnew);
    }
    __syncthreads();                       // s2 complete; all ds_reads of s done

    // write-through publish of this block's 4 KB h-slice (16B chunks)
    if (tid < 256) {
      const int row = tid >> 2, c8 = tid & 3;
      const i32x4 d = *(const i32x4*)&s2[row*32 + c8*8];
      u16* dst = g_hall + (size_t)(t + 1)*B_*H_ + (size_t)row*1024 + blk*32 + c8*8;
      coh_store16(dst, d);
    }
    wait_vm0();                            // own stores at coherence point
    __syncthreads();                       // all waves' stores drained

    // ---- relaxed grid barrier (no cache-maintenance fences) ----
    if (tid == 0) {
      const unsigned arr = __hip_atomic_fetch_add(&g_cnt, 1u, __ATOMIC_RELAXED,
                                                  __HIP_MEMORY_SCOPE_AGENT);
      if (arr == (mygen + 1u)*NLB - 1u) {  // monotonic count: no reset race
        __hip_atomic_store(&g_gen, mygen + 1u, __ATOMIC_RELAXED,
                           __HIP_MEMORY_SCOPE_AGENT);
      } else {
        while (__hip_atomic_load(&g_gen, __ATOMIC_RELAXED,
                                 __HIP_MEMORY_SCOPE_AGENT) <= mygen)
          __builtin_amdgcn_s_sleep(1);
      }
    }
    mygen++;
    __syncthreads();
  }
}

// ---- fallback loop step (no barrier; one launch per t; dispatch-boundary coherence) ----
__global__ __launch_bounds__(512, 1) void mgruf_loop_step(int t, const void* __restrict__ mp)
{
  const int tid = threadIdx.x, lane = tid & 63, w = tid >> 6, blk = blockIdx.x;
  const int m = w & 3, g = w >> 2;
  const int quad = lane >> 4, l15 = lane & 15;
  const int ht = blk*2 + g;
  const int hh = ht*16 + l15;
  __shared__ u16 s[64*SROWH];

  float wc[8];
  {
    const float alpha = 0.5f / (1.0f + __expf(-ldv(mp, hh, g_isbf16)));
    float cacc = alpha; float tmp[8]; tmp[0] = cacc;
#pragma unroll
    for (int i = 1; i < 8; i++) { cacc *= ((float)i + alpha)/(float)(i+1); tmp[i] = cacc; }
#pragma unroll
    for (int j = 0; j < 8; j++) wc[j] = tmp[7 - j];
  }
  const u16* pz = g_Bg + ((size_t)(ht*3 + 0)*48 + 16)*512 + lane*8;
  const u16* pr = pz + (size_t)48*512;
  const u16* pn = pz + (size_t)96*512;

#pragma unroll
  for (int it = 0; it < 16; it++) {
    const int idx = it*512 + tid;
    const int row = idx >> 7, col8 = idx & 127;
    *(short8*)&s[row*SROWH + col8*8] =
        *(const short8*)(g_hall + (size_t)t*B_*H_ + row*1024 + col8*8);
  }
  __syncthreads();

  f32x4 az = {0.f,0.f,0.f,0.f}, ar = az, anh = az;
#pragma unroll 8
  for (int ks = 0; ks < 32; ks++) {
    const short8 a  = *(const short8*)&s[(m*16 + l15)*SROWH + ks*32 + quad*8];
    const short8 bz = *(const short8*)(pz + (size_t)ks*512);
    const short8 br = *(const short8*)(pr + (size_t)ks*512);
    const short8 bn = *(const short8*)(pn + (size_t)ks*512);
    az  = __builtin_amdgcn_mfma_f32_16x16x32_bf16(a, bz, az, 0, 0, 0);
    ar  = __builtin_amdgcn_mfma_f32_16x16x32_bf16(a, br, ar, 0, 0, 0);
    anh = __builtin_amdgcn_mfma_f32_16x16x32_bf16(a, bn, anh, 0, 0, 0);
  }

#pragma unroll
  for (int r = 0; r < 4; r++) {
    const int b = m*16 + quad*4 + r;
    const size_t gxb = ((size_t)t*64 + b)*3072;
    const float gz = g_GX[gxb + hh];
    const float gr = g_GX[gxb + 1024 + hh];
    const float gn = g_GX[gxb + 2048 + hh];
    const float z  = 1.f / (1.f + __expf(-(gz + az[r])));
    const float rr = 1.f / (1.f + __expf(-(gr + ar[r])));
    const float nn = tanhf(gn + rr*anh[r]);
    float mem = 0.f;
#pragma unroll
    for (int j = 0; j < 8; j++) {
      const int sl = (t - 8 + j + 16) & 15;
      mem += wc[j] * g_ring[((size_t)sl*B_ + b)*H_ + hh];
    }
    const float hnew = (1.f - z)*nn + z*mem;
    g_ring[((size_t)(t & 15)*B_ + b)*H_ + hh] = hnew;
    g_hall[(size_t)(t + 1)*B_*H_ + (size_t)b*H_ + hh] = f2b(hnew);
  }
}

// ---- post-GEMM: out[t] = h_t @ Wo + bo.  grid 256 (one t each), 1024 thr ----
__global__ __launch_bounds__(1024) void out_gemm(const void* __restrict__ bov,
                                                 void* __restrict__ out)
{
  const int isb = g_isbf16;
  const int t = blockIdx.x;
  const int tid = threadIdx.x, lane = tid & 63, w = tid >> 6;
  const int m = w & 3, sub = w >> 2;
  const int quad = lane >> 4, l15 = lane & 15;
  __shared__ u16 s[64*SROWH];

#pragma unroll
  for (int it = 0; it < 8; it++) {
    const int idx = it*1024 + tid;
    const int row = idx >> 7, col8 = idx & 127;
    *(short8*)&s[row*SROWH + col8*8] =
        *(const short8*)(g_hall + (size_t)(t + 1)*B_*H_ + row*1024 + col8*8);
  }
  __syncthreads();

  f32x4 acc[8];
#pragma unroll
  for (int nt = 0; nt < 8; nt++) acc[nt] = (f32x4){0.f,0.f,0.f,0.f};

  for (int ks = 0; ks < 32; ks++) {
    const short8 a = *(const short8*)&s[(m*16 + l15)*SROWH + ks*32 + quad*8];
#pragma unroll
    for (int nt = 0; nt < 8; nt++) {
      const short8 b = *(const short8*)(g_Bo + ((size_t)(sub*8 + nt)*32 + ks)*512 + lane*8);
      acc[nt] = __builtin_amdgcn_mfma_f32_16x16x32_bf16(a, b, acc[nt], 0, 0, 0);
    }
  }

#pragma unroll
  for (int nt = 0; nt < 8; nt++) {
    const int oc = (sub*8 + nt)*16 + l15;
    const float bias = ldv(bov, oc, isb);
#pragma unroll
    for (int r = 0; r < 4; r++) {
      const int b = m*16 + quad*4 + r;
      const float v = acc[nt][r] + bias;
      const size_t idx = ((size_t)t*B_ + b)*O_ + oc;
      if (isb) ((u16*)out)[idx] = f2b(v);
      else     ((float*)out)[idx] = v;
    }
  }
}

// ---- H_fin from ring: 512 blocks x 256 thr x 4 elems = 524288 (exact cover) ----
__global__ __launch_bounds__(256) void hfin_kernel(void* __restrict__ out)
{
  const int isb = g_isbf16;
  const int i = blockIdx.x*256 + threadIdx.x;   // < 131072
  const int e   = i*4;                          // < 524288
  const int j   = e >> 16;                      // / (B*H)
  const int rem = e & 65535;
  const int sl  = (T_ - K_ + j) & 15;
  const float4 v = *(const float4*)&g_ring[(size_t)sl*B_*H_ + rem];
  if (isb) {
    ushort4 o4; o4.x = f2b(v.x); o4.y = f2b(v.y); o4.z = f2b(v.z); o4.w = f2b(v.w);
    *(ushort4*)((u16*)out + (size_t)T_*B_*O_ + e) = o4;
  } else {
    *(float4*)((float*)out + (size_t)T_*B_*O_ + e) = v;
  }
}

extern "C" void kernel_launch(void* const* d_in, const int* in_sizes, int n_in,
                              void* d_out, int out_size, void* d_ws, size_t ws_size,
                              hipStream_t stream)
{
  const void* x  = d_in[0];
  const void* hs = d_in[1];
  const void* Wx = d_in[2];
  const void* Wh = d_in[3];
  const void* bv = d_in[4];
  const void* Wo = d_in[5];
  const void* bo = d_in[6];
  const void* mp = d_in[7];
  void* out = d_out;

  probe_dtype<<<dim3(1), dim3(64), 0, stream>>>((const u16*)x);
  prep_x     <<<dim3(8192), dim3(256), 0, stream>>>(x);
  prep_pack_g<<<dim3(2304), dim3(256), 0, stream>>>(Wx, Wh);
  prep_pack_o<<<dim3(256),  dim3(256), 0, stream>>>(Wo);
  prep_ring  <<<dim3(512),  dim3(256), 0, stream>>>(hs);
  gx_gemm    <<<dim3(1024), dim3(1024), 0, stream>>>(bv);

  void* args[] = { (void*)&mp };
  hipError_t err = hipLaunchCooperativeKernel(
      reinterpret_cast<const void*>(&mgruf_loop),
      dim3(NLB), dim3(512), args, 0u, stream);
  if (err != hipSuccess) {
    for (int t = 0; t < T_; t++)
      mgruf_loop_step<<<dim3(NLB), dim3(512), 0, stream>>>(t, mp);
  }

  out_gemm   <<<dim3(256), dim3(1024), 0, stream>>>(bo, out);
  hfin_kernel<<<dim3(512), dim3(256), 0, stream>>>(out);
}